// Round 16
// baseline (7279.636 us; speedup 1.0000x reference)
//
#include <hip/hip_runtime.h>
#include <hip/hip_bf16.h>
#include <stdint.h>

// BayesGRU eval: T=512, B=64, D_IN=1024, D_H=1024.
// Round 16 = R15 champion (5.00ms) + three local reorderings:
//   (1) h bypass loads issued BEFORE x-part MFMAs (x hides under h-burst)
//   (2) rh-lo loads issued before u h-part MFMAs (hide under compute)
//   (3) WT publishes packed via per-wave LDS bounce -> dwordx2 stores
// Layout/topology/flags/transport verbatim R15 (all proven):
//   frag-linear fidx for hA/rh; c-WGs (wg<64) u+cell+update, r-WGs r-gate;
//   WT(sc0sc1) stores + bypass(sc0sc1) loads for same-dispatch data;
//   cached xbf (deep) / cached emb fp32 (shallow) for x.
//   Flags: 64B lines, leader polls. H=fam0 q8; Rlo=fam1/Rhi=fam2 q4.

#define T_STEPS 512
#define BATCH   64
#define DIN     1024
#define DH      1024
#define NWG     128
#define SLAB    65536            // B*DH elements (128KB bf16)

typedef __attribute__((ext_vector_type(8))) short bf16x8;
typedef __attribute__((ext_vector_type(4))) float f32x4;

static __device__ __forceinline__ unsigned short f2bf(float x) {
    union { float f; uint32_t u; } v; v.f = x;
    uint32_t u = v.u;
    return (unsigned short)((u + 0x7FFFu + ((u >> 16) & 1u)) >> 16);
}
static __device__ __forceinline__ float bf2f(unsigned short u) {
    union { uint32_t v; float f; } x; x.v = (uint32_t)u << 16; return x.f;
}
static __device__ __forceinline__ bf16x8 cvt8(float4 a, float4 b) {
    union { bf16x8 v; unsigned d[4]; } u;
    asm("v_cvt_pk_bf16_f32 %0, %1, %2" : "=v"(u.d[0]) : "v"(a.x), "v"(a.y));
    asm("v_cvt_pk_bf16_f32 %0, %1, %2" : "=v"(u.d[1]) : "v"(a.z), "v"(a.w));
    asm("v_cvt_pk_bf16_f32 %0, %1, %2" : "=v"(u.d[2]) : "v"(b.x), "v"(b.y));
    asm("v_cvt_pk_bf16_f32 %0, %1, %2" : "=v"(u.d[3]) : "v"(b.z), "v"(b.w));
    return u.v;
}

// fragment-linear index for the dynamic operands (hA, rh)
static __device__ __forceinline__ int fidx(int row, int k) {
    return ((((row >> 4) * 32 + (k >> 5)) * 64) + (((k >> 3) & 3) * 16) + (row & 15)) * 8
           + (k & 7);
}

// ---- stale-immune transport: WT stores + LLC-bypass loads (proven R3-R15) --
static __device__ __forceinline__ void st_wt_u64(void* p, unsigned long long v) {
    asm volatile("global_store_dwordx2 %0, %1, off sc0 sc1" :: "v"(p), "v"(v) : "memory");
}
static __device__ __forceinline__ bf16x8 ld_llc(const unsigned short* p) {
    bf16x8 r;
    asm volatile("global_load_dwordx4 %0, %1, off sc0 sc1" : "=v"(r) : "v"(p));
    return r;
}
static __device__ __forceinline__ unsigned ld_llc_u16(const unsigned short* p) {
    unsigned r;
    asm volatile("global_load_ushort %0, %1, off sc0 sc1" : "=v"(r) : "v"(p));
    return r;
}
static __device__ __forceinline__ void vwait0() {
    asm volatile("s_waitcnt vmcnt(0)" ::: "memory");
    __builtin_amdgcn_sched_barrier(0);   // rule #18
}
static __device__ __forceinline__ void lwait0() {
    asm volatile("s_waitcnt lgkmcnt(0)" ::: "memory");
    __builtin_amdgcn_sched_barrier(0);   // rule #18
}

// ---- flag wait/post (verbatim R11/R15) -------------------------------------
static __device__ __forceinline__ void wait_fam(const int* cnt, int t, int fam, int quota) {
    const int* b = cnt + t * 128 + fam;
    for (;;) {
        int a0,a1,a2,a3,a4,a5,a6,a7;
        asm volatile("global_load_dword %0, %1, off sc0 sc1" : "=v"(a0) : "v"(b));
        asm volatile("global_load_dword %0, %1, off sc0 sc1" : "=v"(a1) : "v"(b+16));
        asm volatile("global_load_dword %0, %1, off sc0 sc1" : "=v"(a2) : "v"(b+32));
        asm volatile("global_load_dword %0, %1, off sc0 sc1" : "=v"(a3) : "v"(b+48));
        asm volatile("global_load_dword %0, %1, off sc0 sc1" : "=v"(a4) : "v"(b+64));
        asm volatile("global_load_dword %0, %1, off sc0 sc1" : "=v"(a5) : "v"(b+80));
        asm volatile("global_load_dword %0, %1, off sc0 sc1" : "=v"(a6) : "v"(b+96));
        asm volatile("global_load_dword %0, %1, off sc0 sc1" : "=v"(a7) : "v"(b+112));
        asm volatile("s_waitcnt vmcnt(0)" ::: "memory");
        __builtin_amdgcn_sched_barrier(0);
        if (a0>=quota && a1>=quota && a2>=quota && a3>=quota &&
            a4>=quota && a5>=quota && a6>=quota && a7>=quota) break;
        __builtin_amdgcn_s_sleep(2);
    }
}
static __device__ __forceinline__ void wg_wait(const int* cnt, int t, int fam, int quota) {
    if (threadIdx.x == 0) wait_fam(cnt, t, fam, quota);
    __syncthreads();
}
static __device__ __forceinline__ void post_fam(int* cnt, int t, int g, int fam) {
    __hip_atomic_fetch_add(cnt + t * 128 + g * 16 + fam, 1,
                           __ATOMIC_RELAXED, __HIP_MEMORY_SCOPE_AGENT);
}

// ---------------- weight packing (verbatim, verified rounds 1-15) -----------
__global__ __launch_bounds__(256) void gru_pack_weights(
    const float* __restrict__ wihu, const float* __restrict__ wihr,
    const float* __restrict__ wihc, const float* __restrict__ whhu,
    const float* __restrict__ whhr, const float* __restrict__ whhc,
    unsigned short* __restrict__ Wur, unsigned short* __restrict__ Wc)
{
    const int total = 3072 * 2048;
    for (int idx = blockIdx.x * 256 + threadIdx.x; idx < total; idx += gridDim.x * 256) {
        int n = idx >> 11;
        int k = idx & 2047;
        int j = n & 1023;
        float v;
        if (n < 1024)      v = (k < DIN) ? wihu[j*DIN + k] : whhu[j*DH + (k - DIN)];
        else if (n < 2048) v = (k < DIN) ? wihr[j*DIN + k] : whhr[j*DH + (k - DIN)];
        else               v = (k < DIN) ? wihc[j*DIN + k] : whhc[j*DH + (k - DIN)];
        unsigned short bv = f2bf(v);
        int kk = k >> 5, kg = (k >> 3) & 3, r = k & 7;
        if (n < 2048) {
            int b = n >> 4, col = n & 15;
            Wur[((((size_t)kk*128 + b)*4 + kg)*16 + col)*8 + r] = bv;
        } else {
            int nc = n - 2048, b = nc >> 4, col = nc & 15;
            Wc [((((size_t)kk*64 + b)*4 + kg)*16 + col)*8 + r] = bv;
        }
    }
}

// ---------------- emb fp32 -> bf16 (deep path) ------------------------------
__global__ __launch_bounds__(256) void gru_convert_x(
    const float* __restrict__ emb, unsigned short* __restrict__ xbf)
{
    size_t i = (size_t)blockIdx.x * 256 + threadIdx.x;
    float4 v = ((const float4*)emb)[i];
    ushort4 b;
    b.x = f2bf(v.x); b.y = f2bf(v.y); b.z = f2bf(v.z); b.w = f2bf(v.w);
    ((ushort4*)xbf)[i] = b;
}

// ---------------- init: hA[0] = bf16(h0) frag-packed, counters = 0 ----------
__global__ __launch_bounds__(256) void gru_init(
    const float* __restrict__ hx, unsigned short* __restrict__ hA,
    int* __restrict__ cnt)
{
    int i = blockIdx.x * 256 + threadIdx.x;   // 256x256 = 65536
    int row = i >> 10, k = i & 1023;
    hA[fidx(row, k)] = f2bf(hx[i]);
    cnt[i] = 0;
}

// ---------------- persistent GRU kernel -------------------------------------
__global__ __launch_bounds__(256, 1) void gru_persistent(
    const unsigned short* __restrict__ Wur, const unsigned short* __restrict__ Wc,
    const float* __restrict__ emb, const unsigned short* __restrict__ xbf,
    const float* __restrict__ hx,
    const float* __restrict__ bu, const float* __restrict__ br, const float* __restrict__ bc,
    unsigned short* __restrict__ hA, unsigned short* __restrict__ rh,
    float* __restrict__ out, int* __restrict__ cnt, int deep)
{
    __shared__ unsigned short wur_s[32768];   // 64 KB
    __shared__ unsigned short wc_s [32768];   // 64 KB (c-WGs)
    __shared__ __align__(8) unsigned short bounce[1024];   // 2 KB: 4 waves x 256

    const int wg   = blockIdx.x;
    const int tid  = threadIdx.x;
    const int lane = tid & 63;
    const int wid  = tid >> 6;
    const int m0   = wid * 16;
    const int c15  = lane & 15;
    const int kg   = lane >> 4;

    for (int i = tid; i < 4096; i += 256) {
        int kk = i >> 6, j = i & 63;
        *((uint4*)wur_s + i) =
            *(const uint4*)((const char*)Wur + ((size_t)kk*128 + wg)*1024 + j*16);
    }
    if (wg < 64) {
        for (int i = tid; i < 4096; i += 256) {
            int kk = i >> 6, j = i & 63;
            *((uint4*)wc_s + i) =
                *(const uint4*)((const char*)Wc + ((size_t)kk*64 + wg)*1024 + j*16);
        }
    }
    __syncthreads();

    const int v    = wg & 63;
    const int colj = v * 16 + c15;
    // per-wave publish region (frag-linear, contiguous 256 elems = 512B)
    const int regionBase = (wid * 32 + (v >> 1)) * 512 + (v & 1) * 256;
    const int bpos = (c15 >> 3) * 128 + (c15 & 7);   // + (kg*4+i)*8
    unsigned short* bw = bounce + wid * 256;

    if (wg < 64) {
        // ================= c-path: u + cell + h-update =================
        const float bu_ = bu[colj], bc_ = bc[colj];
        float hreg[4];
        #pragma unroll
        for (int i = 0; i < 4; ++i) hreg[i] = hx[(m0 + kg*4 + i) * DH + colj];

        for (int t = 0; t < T_STEPS; ++t) {
            const int par = t & 1;
            const unsigned short* ha   = hA + par * SLAB;
            unsigned short*       hnxt = hA + (par ^ 1) * SLAB;

            f32x4 au = {0.f,0.f,0.f,0.f}, ac = {0.f,0.f,0.f,0.f};
            bf16x8 fr[32];
            bf16x8 fr2[16];

            // --- (1) wait H(t-1), ISSUE h burst first (volatile asm order) ---
            if (t) wg_wait(cnt, t-1, 0, 8);
            const unsigned short* hb = ha + wid * 16384;
            #pragma unroll
            for (int kk = 0; kk < 32; ++kk) fr[kk] = ld_llc(hb + kk * 512 + lane * 8);

            // --- x-parts of u and c (cached) run UNDER the h burst ---
            if (deep) {
                const unsigned short* xp =
                    xbf + ((size_t)t * BATCH + (m0 + c15)) * DIN + kg * 8;
                #pragma unroll
                for (int kk = 0; kk < 32; ++kk) {
                    bf16x8 f = *(const bf16x8*)(xp + kk * 32);
                    au = __builtin_amdgcn_mfma_f32_16x16x32_bf16(
                             f, *(const bf16x8*)(wur_s + kk*512 + lane*8), au, 0, 0, 0);
                    ac = __builtin_amdgcn_mfma_f32_16x16x32_bf16(
                             f, *(const bf16x8*)(wc_s + kk*512 + lane*8), ac, 0, 0, 0);
                }
            } else {
                const float* xp = emb + ((size_t)t * BATCH + (m0 + c15)) * DIN + kg * 8;
                #pragma unroll
                for (int kk = 0; kk < 32; ++kk) {
                    float4 a = *(const float4*)(xp + kk * 32);
                    float4 b = *(const float4*)(xp + kk * 32 + 4);
                    bf16x8 f = cvt8(a, b);
                    au = __builtin_amdgcn_mfma_f32_16x16x32_bf16(
                             f, *(const bf16x8*)(wur_s + kk*512 + lane*8), au, 0, 0, 0);
                    ac = __builtin_amdgcn_mfma_f32_16x16x32_bf16(
                             f, *(const bf16x8*)(wc_s + kk*512 + lane*8), ac, 0, 0, 0);
                }
            }
            vwait0();   // h frags (and x) landed

            // --- (2) wait R-lo, issue rh-lo, then u h-part under the burst ---
            const unsigned short* rb = rh + wid * 16384;
            wg_wait(cnt, t, 1, 4);
            #pragma unroll
            for (int kk = 0; kk < 16; ++kk) fr2[kk] = ld_llc(rb + kk * 512 + lane * 8);

            #pragma unroll
            for (int kk = 0; kk < 32; ++kk)
                au = __builtin_amdgcn_mfma_f32_16x16x32_bf16(
                         fr[kk], *(const bf16x8*)(wur_s + (kk+32)*512 + lane*8), au, 0, 0, 0);
            float ureg[4];
            #pragma unroll
            for (int i = 0; i < 4; ++i)
                ureg[i] = 1.f / (1.f + __expf(-(au[i] + bu_)));

            vwait0();
            #pragma unroll
            for (int kk = 0; kk < 16; ++kk)
                ac = __builtin_amdgcn_mfma_f32_16x16x32_bf16(
                         fr2[kk], *(const bf16x8*)(wc_s + (kk+32)*512 + lane*8), ac, 0, 0, 0);

            wg_wait(cnt, t, 2, 4);
            #pragma unroll
            for (int kk = 0; kk < 16; ++kk) fr2[kk] = ld_llc(rb + (kk+16) * 512 + lane * 8);
            vwait0();
            #pragma unroll
            for (int kk = 0; kk < 16; ++kk)
                ac = __builtin_amdgcn_mfma_f32_16x16x32_bf16(
                         fr2[kk], *(const bf16x8*)(wc_s + (kk+48)*512 + lane*8), ac, 0, 0, 0);

            // --- update; (3) packed publish via LDS bounce ---
            float hnv[4];
            #pragma unroll
            for (int i = 0; i < 4; ++i) {
                float pre = ac[i] + bc_;
                float e   = __expf(2.f * pre);
                float cel = 1.f - 2.f / (e + 1.f);          // tanh
                float hn  = (1.f - ureg[i]) * hreg[i] + ureg[i] * cel;
                hreg[i] = hn;
                hnv[i]  = hn;
                bw[bpos + (kg * 4 + i) * 8] = f2bf(hn);
            }
            lwait0();
            {
                unsigned long long pk = *(const unsigned long long*)(bw + lane * 4);
                st_wt_u64(hnxt + regionBase + lane * 4, pk);
            }
            asm volatile("s_waitcnt vmcnt(0)" ::: "memory");
            __syncthreads();
            if (tid == 0) post_fam(cnt, t, wg >> 3, 0);

            float* out_t = out + (size_t)t * SLAB;          // write-only, off-path
            #pragma unroll
            for (int i = 0; i < 4; ++i) {
                int row = m0 + kg * 4 + i;
                out_t[row * DH + colj] = hnv[i];
                if (t == T_STEPS - 1)
                    out[(size_t)T_STEPS * SLAB + row * DH + colj] = hnv[i];
            }
        }
    } else {
        // ================= r-path: reset gate -> rh =================
        const float br_ = br[colj];
        for (int t = 0; t < T_STEPS; ++t) {
            const int par = t & 1;
            const unsigned short* ha = hA + par * SLAB;

            f32x4 ar = {0.f,0.f,0.f,0.f};
            bf16x8 fr[32];

            // --- (1) wait H(t-1), issue h burst (+ own-col scalars) first ---
            if (t) wg_wait(cnt, t-1, 0, 8);
            const unsigned short* hb = ha + wid * 16384;
            unsigned hp16[4];
            #pragma unroll
            for (int i = 0; i < 4; ++i)
                hp16[i] = ld_llc_u16(ha + fidx(m0 + kg*4 + i, colj));
            #pragma unroll
            for (int kk = 0; kk < 32; ++kk) fr[kk] = ld_llc(hb + kk * 512 + lane * 8);

            // --- x-part of r (cached) under the burst ---
            if (deep) {
                const unsigned short* xp =
                    xbf + ((size_t)t * BATCH + (m0 + c15)) * DIN + kg * 8;
                #pragma unroll
                for (int kk = 0; kk < 32; ++kk)
                    ar = __builtin_amdgcn_mfma_f32_16x16x32_bf16(
                             *(const bf16x8*)(xp + kk * 32),
                             *(const bf16x8*)(wur_s + kk*512 + lane*8), ar, 0, 0, 0);
            } else {
                const float* xp = emb + ((size_t)t * BATCH + (m0 + c15)) * DIN + kg * 8;
                #pragma unroll
                for (int kk = 0; kk < 32; ++kk) {
                    float4 a = *(const float4*)(xp + kk * 32);
                    float4 b = *(const float4*)(xp + kk * 32 + 4);
                    ar = __builtin_amdgcn_mfma_f32_16x16x32_bf16(
                             cvt8(a, b), *(const bf16x8*)(wur_s + kk*512 + lane*8),
                             ar, 0, 0, 0);
                }
            }
            vwait0();

            // --- h-part of r ---
            #pragma unroll
            for (int kk = 0; kk < 32; ++kk)
                ar = __builtin_amdgcn_mfma_f32_16x16x32_bf16(
                         fr[kk], *(const bf16x8*)(wur_s + (kk+32)*512 + lane*8),
                         ar, 0, 0, 0);

            // --- (3) packed rh publish via LDS bounce ---
            #pragma unroll
            for (int i = 0; i < 4; ++i) {
                float s = 1.f / (1.f + __expf(-(ar[i] + br_)));
                bw[bpos + (kg * 4 + i) * 8] =
                    f2bf(s * bf2f((unsigned short)hp16[i]));
            }
            lwait0();
            {
                unsigned long long pk = *(const unsigned long long*)(bw + lane * 4);
                st_wt_u64(rh + regionBase + lane * 4, pk);
            }
            asm volatile("s_waitcnt vmcnt(0)" ::: "memory");
            __syncthreads();
            if (tid == 0) {
                if (v < 32) post_fam(cnt, t, v >> 2, 1);
                else        post_fam(cnt, t, (v - 32) >> 2, 2);
            }
        }
    }
}

// ---------------- host launch ----------------------------------------------
extern "C" void kernel_launch(void* const* d_in, const int* in_sizes, int n_in,
                              void* d_out, int out_size, void* d_ws, size_t ws_size,
                              hipStream_t stream)
{
    const float* emb  = (const float*)d_in[0];
    const float* hx   = (const float*)d_in[1];
    const float* wihu = (const float*)d_in[2];
    const float* wihr = (const float*)d_in[3];
    const float* wihc = (const float*)d_in[4];
    const float* whhu = (const float*)d_in[5];
    const float* whhr = (const float*)d_in[6];
    const float* whhc = (const float*)d_in[7];
    const float* bu   = (const float*)d_in[8];
    const float* br   = (const float*)d_in[9];
    const float* bc   = (const float*)d_in[10];
    float* out = (float*)d_out;
    char*  ws  = (char*)d_ws;

    // ws layout (bytes) — identical to R11/R15:
    unsigned short* Wur = (unsigned short*)(ws + 0);          // 8 MiB
    unsigned short* Wc  = (unsigned short*)(ws + 8388608);    // 4 MiB
    int*            cnt = (int*)(ws + 12582912);              // 256 KiB flag lines
    unsigned short* hA  = (unsigned short*)(ws + 12845056);   // 256 KiB (2 slabs)
    unsigned short* rhb = (unsigned short*)(ws + 13107200);   // 128 KiB
    unsigned short* xbf = (unsigned short*)(ws + 16777216);   // 64 MiB (deep)
    const int deep = (ws_size >= 83886080ull) ? 1 : 0;

    gru_pack_weights<<<1024, 256, 0, stream>>>(wihu, wihr, wihc, whhu, whhr, whhc, Wur, Wc);
    if (deep) gru_convert_x<<<32768, 256, 0, stream>>>(emb, xbf);
    gru_init<<<256, 256, 0, stream>>>(hx, hA, cnt);
    gru_persistent<<<NWG, 256, 0, stream>>>(Wur, Wc, emb, xbf, hx, bu, br, bc,
                                            hA, rhb, out, cnt, deep);
}

// Round 18
// 4868.027 us; speedup vs baseline: 1.4954x; 1.4954x over previous
//
#include <hip/hip_runtime.h>
#include <hip/hip_bf16.h>
#include <stdint.h>

// BayesGRU eval: T=512, B=64, D_IN=1024, D_H=1024.
// Round 18 = R15 champion (5.00ms) + merged single R-wait:
//   r-WGs post ONE flag family (fam1, quota 8); c-WGs wait once and read all
//   32 rh fragments in one burst (u h-part + sigmoid hide under it).
//   Deletes one leader poll round-trip + one __syncthreads per step.
//   Poll backoff s_sleep(2) -> s_sleep(1).
// Everything else verbatim R15 (proven): frag-linear fidx for hA/rh;
// c-WGs (wg<64) u+cell+update, r-WGs (wg>=64) r-gate; WT(sc0sc1) stores +
// bypass(sc0sc1) loads for all same-dispatch data; cached xbf (deep) /
// cached emb fp32 (shallow) for x; flags 64B lines, leader-only polls;
// H=fam0 q8, R=fam1 q8. Out stores after H-post (off critical path).

#define T_STEPS 512
#define BATCH   64
#define DIN     1024
#define DH      1024
#define NWG     128
#define SLAB    65536            // B*DH elements (128KB bf16)

typedef __attribute__((ext_vector_type(8))) short bf16x8;
typedef __attribute__((ext_vector_type(4))) float f32x4;

static __device__ __forceinline__ unsigned short f2bf(float x) {
    union { float f; uint32_t u; } v; v.f = x;
    uint32_t u = v.u;
    return (unsigned short)((u + 0x7FFFu + ((u >> 16) & 1u)) >> 16);
}
static __device__ __forceinline__ float bf2f(unsigned short u) {
    union { uint32_t v; float f; } x; x.v = (uint32_t)u << 16; return x.f;
}
static __device__ __forceinline__ bf16x8 cvt8(float4 a, float4 b) {
    union { bf16x8 v; unsigned d[4]; } u;
    asm("v_cvt_pk_bf16_f32 %0, %1, %2" : "=v"(u.d[0]) : "v"(a.x), "v"(a.y));
    asm("v_cvt_pk_bf16_f32 %0, %1, %2" : "=v"(u.d[1]) : "v"(a.z), "v"(a.w));
    asm("v_cvt_pk_bf16_f32 %0, %1, %2" : "=v"(u.d[2]) : "v"(b.x), "v"(b.y));
    asm("v_cvt_pk_bf16_f32 %0, %1, %2" : "=v"(u.d[3]) : "v"(b.z), "v"(b.w));
    return u.v;
}

// fragment-linear index for the dynamic operands (hA, rh)
static __device__ __forceinline__ int fidx(int row, int k) {
    return ((((row >> 4) * 32 + (k >> 5)) * 64) + (((k >> 3) & 3) * 16) + (row & 15)) * 8
           + (k & 7);
}

// ---- stale-immune transport: WT stores + LLC-bypass loads (proven R3-R16) --
static __device__ __forceinline__ void st_wt_u16(void* p, unsigned v) {
    asm volatile("global_store_short %0, %1, off sc0 sc1" :: "v"(p), "v"(v) : "memory");
}
static __device__ __forceinline__ bf16x8 ld_llc(const unsigned short* p) {
    bf16x8 r;
    asm volatile("global_load_dwordx4 %0, %1, off sc0 sc1" : "=v"(r) : "v"(p));
    return r;
}
static __device__ __forceinline__ unsigned ld_llc_u16(const unsigned short* p) {
    unsigned r;
    asm volatile("global_load_ushort %0, %1, off sc0 sc1" : "=v"(r) : "v"(p));
    return r;
}
static __device__ __forceinline__ void vwait0() {
    asm volatile("s_waitcnt vmcnt(0)" ::: "memory");
    __builtin_amdgcn_sched_barrier(0);   // rule #18
}

// ---- flag wait/post: line(t,g)=cnt+t*128+g*16 ints; fam dword 0..1 ---------
static __device__ __forceinline__ void wait_fam(const int* cnt, int t, int fam, int quota) {
    const int* b = cnt + t * 128 + fam;
    for (;;) {
        int a0,a1,a2,a3,a4,a5,a6,a7;
        asm volatile("global_load_dword %0, %1, off sc0 sc1" : "=v"(a0) : "v"(b));
        asm volatile("global_load_dword %0, %1, off sc0 sc1" : "=v"(a1) : "v"(b+16));
        asm volatile("global_load_dword %0, %1, off sc0 sc1" : "=v"(a2) : "v"(b+32));
        asm volatile("global_load_dword %0, %1, off sc0 sc1" : "=v"(a3) : "v"(b+48));
        asm volatile("global_load_dword %0, %1, off sc0 sc1" : "=v"(a4) : "v"(b+64));
        asm volatile("global_load_dword %0, %1, off sc0 sc1" : "=v"(a5) : "v"(b+80));
        asm volatile("global_load_dword %0, %1, off sc0 sc1" : "=v"(a6) : "v"(b+96));
        asm volatile("global_load_dword %0, %1, off sc0 sc1" : "=v"(a7) : "v"(b+112));
        asm volatile("s_waitcnt vmcnt(0)" ::: "memory");
        __builtin_amdgcn_sched_barrier(0);
        if (a0>=quota && a1>=quota && a2>=quota && a3>=quota &&
            a4>=quota && a5>=quota && a6>=quota && a7>=quota) break;
        __builtin_amdgcn_s_sleep(1);
    }
}
static __device__ __forceinline__ void wg_wait(const int* cnt, int t, int fam, int quota) {
    if (threadIdx.x == 0) wait_fam(cnt, t, fam, quota);
    __syncthreads();
}
static __device__ __forceinline__ void post_fam(int* cnt, int t, int g, int fam) {
    __hip_atomic_fetch_add(cnt + t * 128 + g * 16 + fam, 1,
                           __ATOMIC_RELAXED, __HIP_MEMORY_SCOPE_AGENT);
}

// ---------------- weight packing (verbatim, verified rounds 1-17) -----------
// Wur: [kk=64][b=128][kg=4][col=16][8] (u cols: b<64, r cols: b>=64)
// Wc : [kk=64][b=64 ][kg=4][col=16][8], K order = [x | h].
__global__ __launch_bounds__(256) void gru_pack_weights(
    const float* __restrict__ wihu, const float* __restrict__ wihr,
    const float* __restrict__ wihc, const float* __restrict__ whhu,
    const float* __restrict__ whhr, const float* __restrict__ whhc,
    unsigned short* __restrict__ Wur, unsigned short* __restrict__ Wc)
{
    const int total = 3072 * 2048;
    for (int idx = blockIdx.x * 256 + threadIdx.x; idx < total; idx += gridDim.x * 256) {
        int n = idx >> 11;
        int k = idx & 2047;
        int j = n & 1023;
        float v;
        if (n < 1024)      v = (k < DIN) ? wihu[j*DIN + k] : whhu[j*DH + (k - DIN)];
        else if (n < 2048) v = (k < DIN) ? wihr[j*DIN + k] : whhr[j*DH + (k - DIN)];
        else               v = (k < DIN) ? wihc[j*DIN + k] : whhc[j*DH + (k - DIN)];
        unsigned short bv = f2bf(v);
        int kk = k >> 5, kg = (k >> 3) & 3, r = k & 7;
        if (n < 2048) {
            int b = n >> 4, col = n & 15;
            Wur[((((size_t)kk*128 + b)*4 + kg)*16 + col)*8 + r] = bv;
        } else {
            int nc = n - 2048, b = nc >> 4, col = nc & 15;
            Wc [((((size_t)kk*64 + b)*4 + kg)*16 + col)*8 + r] = bv;
        }
    }
}

// ---------------- emb fp32 -> bf16 (deep path) ------------------------------
__global__ __launch_bounds__(256) void gru_convert_x(
    const float* __restrict__ emb, unsigned short* __restrict__ xbf)
{
    size_t i = (size_t)blockIdx.x * 256 + threadIdx.x;
    float4 v = ((const float4*)emb)[i];
    ushort4 b;
    b.x = f2bf(v.x); b.y = f2bf(v.y); b.z = f2bf(v.z); b.w = f2bf(v.w);
    ((ushort4*)xbf)[i] = b;
}

// ---------------- init: hA[0] = bf16(h0) frag-packed, counters = 0 ----------
__global__ __launch_bounds__(256) void gru_init(
    const float* __restrict__ hx, unsigned short* __restrict__ hA,
    int* __restrict__ cnt)
{
    int i = blockIdx.x * 256 + threadIdx.x;   // 256x256 = 65536
    int row = i >> 10, k = i & 1023;
    hA[fidx(row, k)] = f2bf(hx[i]);
    cnt[i] = 0;
}

// ---------------- persistent GRU kernel -------------------------------------
// c-WG (wg<64): u-gate + cell + h-update for cols [16wg,16wg+16).
// r-WG (wg>=64): r-gate for cols [16(wg-64),...); publishes rh.
__global__ __launch_bounds__(256, 1) void gru_persistent(
    const unsigned short* __restrict__ Wur, const unsigned short* __restrict__ Wc,
    const float* __restrict__ emb, const unsigned short* __restrict__ xbf,
    const float* __restrict__ hx,
    const float* __restrict__ bu, const float* __restrict__ br, const float* __restrict__ bc,
    unsigned short* __restrict__ hA, unsigned short* __restrict__ rh,
    float* __restrict__ out, int* __restrict__ cnt, int deep)
{
    __shared__ unsigned short wur_s[32768];   // 64 KB: this WG's 16-col u/r slice
    __shared__ unsigned short wc_s [32768];   // 64 KB: c-WGs' 16-col c slice

    const int wg   = blockIdx.x;
    const int tid  = threadIdx.x;
    const int lane = tid & 63;
    const int wid  = tid >> 6;
    const int m0   = wid * 16;
    const int c15  = lane & 15;
    const int kg   = lane >> 4;

    for (int i = tid; i < 4096; i += 256) {
        int kk = i >> 6, j = i & 63;
        *((uint4*)wur_s + i) =
            *(const uint4*)((const char*)Wur + ((size_t)kk*128 + wg)*1024 + j*16);
    }
    if (wg < 64) {
        for (int i = tid; i < 4096; i += 256) {
            int kk = i >> 6, j = i & 63;
            *((uint4*)wc_s + i) =
                *(const uint4*)((const char*)Wc + ((size_t)kk*64 + wg)*1024 + j*16);
        }
    }
    __syncthreads();

    const int v    = wg & 63;
    const int colj = v * 16 + c15;

    if (wg < 64) {
        // ================= c-path: u + cell + h-update =================
        const float bu_ = bu[colj], bc_ = bc[colj];
        float hreg[4];
        #pragma unroll
        for (int i = 0; i < 4; ++i) hreg[i] = hx[(m0 + kg*4 + i) * DH + colj];

        for (int t = 0; t < T_STEPS; ++t) {
            const int par = t & 1;
            const unsigned short* ha   = hA + par * SLAB;
            unsigned short*       hnxt = hA + (par ^ 1) * SLAB;

            f32x4 au = {0.f,0.f,0.f,0.f}, ac = {0.f,0.f,0.f,0.f};
            bf16x8 fr[32];

            // --- x-parts of u and c (cached; overlaps waiting time) ---
            if (deep) {
                const unsigned short* xp =
                    xbf + ((size_t)t * BATCH + (m0 + c15)) * DIN + kg * 8;
                #pragma unroll
                for (int kk = 0; kk < 32; ++kk) {
                    bf16x8 f = *(const bf16x8*)(xp + kk * 32);
                    au = __builtin_amdgcn_mfma_f32_16x16x32_bf16(
                             f, *(const bf16x8*)(wur_s + kk*512 + lane*8), au, 0, 0, 0);
                    ac = __builtin_amdgcn_mfma_f32_16x16x32_bf16(
                             f, *(const bf16x8*)(wc_s + kk*512 + lane*8), ac, 0, 0, 0);
                }
            } else {
                const float* xp = emb + ((size_t)t * BATCH + (m0 + c15)) * DIN + kg * 8;
                #pragma unroll
                for (int kk = 0; kk < 32; ++kk) {
                    float4 a = *(const float4*)(xp + kk * 32);
                    float4 b = *(const float4*)(xp + kk * 32 + 4);
                    bf16x8 f = cvt8(a, b);
                    au = __builtin_amdgcn_mfma_f32_16x16x32_bf16(
                             f, *(const bf16x8*)(wur_s + kk*512 + lane*8), au, 0, 0, 0);
                    ac = __builtin_amdgcn_mfma_f32_16x16x32_bf16(
                             f, *(const bf16x8*)(wc_s + kk*512 + lane*8), ac, 0, 0, 0);
                }
            }

            // --- h-part of u (bypass, frag-linear: 1KB contiguous/instr) ---
            if (t) wg_wait(cnt, t-1, 0, 8);
            const unsigned short* hb = ha + wid * 16384;    // row-block slab
            #pragma unroll
            for (int kk = 0; kk < 32; ++kk) fr[kk] = ld_llc(hb + kk * 512 + lane * 8);
            vwait0();
            #pragma unroll
            for (int kk = 0; kk < 32; ++kk)
                au = __builtin_amdgcn_mfma_f32_16x16x32_bf16(
                         fr[kk], *(const bf16x8*)(wur_s + (kk+32)*512 + lane*8), au, 0, 0, 0);

            // --- single R wait; issue full rh burst; sigmoid hides under it ---
            const unsigned short* rb = rh + wid * 16384;
            wg_wait(cnt, t, 1, 8);
            #pragma unroll
            for (int kk = 0; kk < 32; ++kk) fr[kk] = ld_llc(rb + kk * 512 + lane * 8);

            float ureg[4];
            #pragma unroll
            for (int i = 0; i < 4; ++i)
                ureg[i] = 1.f / (1.f + __expf(-(au[i] + bu_)));

            vwait0();
            #pragma unroll
            for (int kk = 0; kk < 32; ++kk)
                ac = __builtin_amdgcn_mfma_f32_16x16x32_bf16(
                         fr[kk], *(const bf16x8*)(wc_s + (kk+32)*512 + lane*8), ac, 0, 0, 0);

            // --- update, publish h (frag-linear WT), post H; out after ---
            float hnv[4];
            #pragma unroll
            for (int i = 0; i < 4; ++i) {
                int row = m0 + kg * 4 + i;
                float pre = ac[i] + bc_;
                float e   = __expf(2.f * pre);
                float cel = 1.f - 2.f / (e + 1.f);          // tanh
                float hn  = (1.f - ureg[i]) * hreg[i] + ureg[i] * cel;
                hreg[i] = hn;
                hnv[i]  = hn;
                st_wt_u16(hnxt + fidx(row, colj), (unsigned)f2bf(hn));
            }
            asm volatile("s_waitcnt vmcnt(0)" ::: "memory");
            __syncthreads();
            if (tid == 0) post_fam(cnt, t, wg >> 3, 0);

            float* out_t = out + (size_t)t * SLAB;          // write-only, off-path
            #pragma unroll
            for (int i = 0; i < 4; ++i) {
                int row = m0 + kg * 4 + i;
                out_t[row * DH + colj] = hnv[i];
                if (t == T_STEPS - 1)
                    out[(size_t)T_STEPS * SLAB + row * DH + colj] = hnv[i];
            }
        }
    } else {
        // ================= r-path: reset gate -> rh =================
        const float br_ = br[colj];
        for (int t = 0; t < T_STEPS; ++t) {
            const int par = t & 1;
            const unsigned short* ha = hA + par * SLAB;

            f32x4 ar = {0.f,0.f,0.f,0.f};
            bf16x8 fr[32];

            // --- x-part of r (cached; overlaps waiting time) ---
            if (deep) {
                const unsigned short* xp =
                    xbf + ((size_t)t * BATCH + (m0 + c15)) * DIN + kg * 8;
                #pragma unroll
                for (int kk = 0; kk < 32; ++kk)
                    ar = __builtin_amdgcn_mfma_f32_16x16x32_bf16(
                             *(const bf16x8*)(xp + kk * 32),
                             *(const bf16x8*)(wur_s + kk*512 + lane*8), ar, 0, 0, 0);
            } else {
                const float* xp = emb + ((size_t)t * BATCH + (m0 + c15)) * DIN + kg * 8;
                #pragma unroll
                for (int kk = 0; kk < 32; ++kk) {
                    float4 a = *(const float4*)(xp + kk * 32);
                    float4 b = *(const float4*)(xp + kk * 32 + 4);
                    ar = __builtin_amdgcn_mfma_f32_16x16x32_bf16(
                             cvt8(a, b), *(const bf16x8*)(wur_s + kk*512 + lane*8),
                             ar, 0, 0, 0);
                }
            }

            // --- h-part of r (frag-linear bypass; + own-col h scalars) ---
            if (t) wg_wait(cnt, t-1, 0, 8);
            const unsigned short* hb = ha + wid * 16384;
            unsigned hp16[4];
            #pragma unroll
            for (int i = 0; i < 4; ++i)
                hp16[i] = ld_llc_u16(ha + fidx(m0 + kg*4 + i, colj));
            #pragma unroll
            for (int kk = 0; kk < 32; ++kk) fr[kk] = ld_llc(hb + kk * 512 + lane * 8);
            vwait0();
            #pragma unroll
            for (int kk = 0; kk < 32; ++kk)
                ar = __builtin_amdgcn_mfma_f32_16x16x32_bf16(
                         fr[kk], *(const bf16x8*)(wur_s + (kk+32)*512 + lane*8),
                         ar, 0, 0, 0);

            // --- publish rh (frag-linear WT), post R (single family q8) ---
            #pragma unroll
            for (int i = 0; i < 4; ++i) {
                int row = m0 + kg * 4 + i;
                float s = 1.f / (1.f + __expf(-(ar[i] + br_)));
                st_wt_u16(rh + fidx(row, colj),
                          (unsigned)f2bf(s * bf2f((unsigned short)hp16[i])));
            }
            asm volatile("s_waitcnt vmcnt(0)" ::: "memory");
            __syncthreads();
            if (tid == 0) post_fam(cnt, t, v >> 3, 1);
        }
    }
}

// ---------------- host launch ----------------------------------------------
extern "C" void kernel_launch(void* const* d_in, const int* in_sizes, int n_in,
                              void* d_out, int out_size, void* d_ws, size_t ws_size,
                              hipStream_t stream)
{
    const float* emb  = (const float*)d_in[0];
    const float* hx   = (const float*)d_in[1];
    const float* wihu = (const float*)d_in[2];
    const float* wihr = (const float*)d_in[3];
    const float* wihc = (const float*)d_in[4];
    const float* whhu = (const float*)d_in[5];
    const float* whhr = (const float*)d_in[6];
    const float* whhc = (const float*)d_in[7];
    const float* bu   = (const float*)d_in[8];
    const float* br   = (const float*)d_in[9];
    const float* bc   = (const float*)d_in[10];
    float* out = (float*)d_out;
    char*  ws  = (char*)d_ws;

    // ws layout (bytes) — identical to R11/R15:
    unsigned short* Wur = (unsigned short*)(ws + 0);          // 8 MiB
    unsigned short* Wc  = (unsigned short*)(ws + 8388608);    // 4 MiB
    int*            cnt = (int*)(ws + 12582912);              // 256 KiB flag lines
    unsigned short* hA  = (unsigned short*)(ws + 12845056);   // 256 KiB (2 slabs)
    unsigned short* rhb = (unsigned short*)(ws + 13107200);   // 128 KiB
    unsigned short* xbf = (unsigned short*)(ws + 16777216);   // 64 MiB (deep)
    const int deep = (ws_size >= 83886080ull) ? 1 : 0;

    gru_pack_weights<<<1024, 256, 0, stream>>>(wihu, wihr, wihc, whhu, whhr, whhc, Wur, Wc);
    if (deep) gru_convert_x<<<32768, 256, 0, stream>>>(emb, xbf);
    gru_init<<<256, 256, 0, stream>>>(hx, hA, cnt);
    gru_persistent<<<NWG, 256, 0, stream>>>(Wur, Wc, emb, xbf, hx, bu, br, bc,
                                            hA, rhb, out, cnt, deep);
}